// Round 9
// baseline (527.510 us; speedup 1.0000x reference)
//
#include <hip/hip_runtime.h>
#include <hip/hip_fp16.h>

// EdgeConvEncoder R17 (on R16):
//  - hist atomic service (70us TCC RMW floor for 1.5M atomics) split 3 ways:
//    e0 in preproc (hidden under streaming), e1 fire-early/consume-late INSIDE
//    gemm0's blocks (atomic issued before LDS staging, rank written after
//    C-write -> overlaps MFMA; NOT R15's serialized tail blocks), e2 in gemm1.
//  - scan_pass3/rowptr eliminated: scatter uses excl[d]+bsum[d>>8]+rank;
//    finalize reads counts straight from hist. Per-layer just-in-time
//    scan+scatter so each layer's sort finishes right before its attn.
//  - edge_attn unchanged (at gather-service ceiling ~69.5us).

typedef _Float16 f16x8 __attribute__((ext_vector_type(8)));
typedef unsigned int u32x4 __attribute__((ext_vector_type(4)));
typedef float f32x4 __attribute__((ext_vector_type(4)));
typedef float f32x2 __attribute__((ext_vector_type(2)));

__device__ __forceinline__ unsigned short f2h(float f) {
  __half h = __float2half(f);
  return *reinterpret_cast<unsigned short*>(&h);
}
__device__ __forceinline__ __half2 ash2(unsigned w) {
  return *reinterpret_cast<__half2*>(&w);
}

// ---------------- weight packing ----------------
__device__ __forceinline__ void pack_w_seg(const float* __restrict__ wq,
                                           const float* __restrict__ wk,
                                           const float* __restrict__ wv,
                                           unsigned short* __restrict__ dst,
                                           int IN, int O, float kscale, int id) {
  int kchunks = IN >> 5, nchunks = O >> 4;
  int total = 6 * nchunks * kchunks * 64;
  if (id >= total) return;
  int lane = id & 63;
  int frag = id >> 6;
  int kc = frag % kchunks;
  int nc = (frag / kchunks) % nchunks;
  int mat = frag / (kchunks * nchunks);
  const float* w = (mat % 3 == 0) ? wq : (mat % 3 == 1) ? wk : wv;
  float mul = (mat % 3 == 1) ? kscale : 1.0f;
  int n = nc * 16 + (lane & 15);
  int k0 = kc * 32 + (lane >> 4) * 8;
  unsigned short tmp[8];
#pragma unroll
  for (int j = 0; j < 8; ++j) {
    int row = k0 + j;
    float bot = w[(size_t)(IN + row) * O + n];
    float val = (mat < 3) ? (w[(size_t)row * O + n] - bot) : bot;
    tmp[j] = f2h(val * mul);
  }
  uint4 o;
  o.x = (unsigned)tmp[0] | ((unsigned)tmp[1] << 16);
  o.y = (unsigned)tmp[2] | ((unsigned)tmp[3] << 16);
  o.z = (unsigned)tmp[4] | ((unsigned)tmp[5] << 16);
  o.w = (unsigned)tmp[6] | ((unsigned)tmp[7] << 16);
  reinterpret_cast<uint4*>(dst)[id] = o;
}

__device__ __forceinline__ void pack_b_seg(const float* __restrict__ bq,
                                           const float* __restrict__ bk,
                                           const float* __restrict__ bv, float kscale, int O,
                                           float* __restrict__ out, int i) {
  int mat = i / O, c = i % O;
  float v = 0.f;
  if (mat == 0) v = bq[c];
  else if (mat == 1) v = bk[c] * kscale;
  else if (mat == 2) v = bv[c];
  out[i] = v;
}

// ---------------- fused preprocessing + e0 histogram ----------------
__global__ void preproc(
    const int* __restrict__ e0, int E, int* __restrict__ hist, int* __restrict__ rank,
    uint4* __restrict__ za, int na, uint4* __restrict__ zb, int nb,
    const float* __restrict__ x, unsigned short* __restrict__ xb, int n8,
    const float* __restrict__ wq0, const float* __restrict__ wk0, const float* __restrict__ wv0,
    const float* __restrict__ wq1, const float* __restrict__ wk1, const float* __restrict__ wv1,
    const float* __restrict__ wq2, const float* __restrict__ wk2, const float* __restrict__ wv2,
    unsigned short* __restrict__ wp0, unsigned short* __restrict__ wp1,
    unsigned short* __restrict__ wp2,
    const float* __restrict__ bq0, const float* __restrict__ bk0, const float* __restrict__ bv0,
    const float* __restrict__ bq1, const float* __restrict__ bk1, const float* __restrict__ bv1,
    const float* __restrict__ bq2, const float* __restrict__ bk2, const float* __restrict__ bv2,
    float* __restrict__ bias0, float* __restrict__ bias1, float* __restrict__ bias2,
    float sc16, float sc8) {
  const int tid = blockIdx.x * blockDim.x + threadIdx.x;
  const int stride = gridDim.x * blockDim.x;

  // e0 histogram + rank; latency hides under streaming below
  for (int i = tid; i < E; i += stride) rank[i] = atomicAdd(&hist[e0[E + i]], 1);

  const uint4 Z = make_uint4(0u, 0u, 0u, 0u);
  for (int j = tid; j < na; j += stride) za[j] = Z;
  for (int j = tid; j < nb; j += stride) zb[j] = Z;
  for (int j = tid; j < n8; j += stride) {
    float4 a = reinterpret_cast<const float4*>(x)[2 * j];
    float4 b = reinterpret_cast<const float4*>(x)[2 * j + 1];
    uint4 o;
    o.x = (unsigned)f2h(a.x) | ((unsigned)f2h(a.y) << 16);
    o.y = (unsigned)f2h(a.z) | ((unsigned)f2h(a.w) << 16);
    o.z = (unsigned)f2h(b.x) | ((unsigned)f2h(b.y) << 16);
    o.w = (unsigned)f2h(b.z) | ((unsigned)f2h(b.w) << 16);
    reinterpret_cast<uint4*>(xb)[j] = o;
  }
  if (tid < 12288) pack_w_seg(wq0, wk0, wv0, wp0, 128, 128, sc16, tid);
  else if (tid < 18432) pack_w_seg(wq1, wk1, wv1, wp1, 128, 64, sc8, tid - 12288);
  else if (tid < 24576) pack_w_seg(wq2, wk2, wv2, wp2, 64, 128, sc16, tid - 18432);
  else if (tid < 24576 + 1920) {
    int i = tid - 24576;
    if (i < 768) pack_b_seg(bq0, bk0, bv0, sc16, 128, bias0, i);
    else if (i < 1152) pack_b_seg(bq1, bk1, bv1, sc8, 64, bias1, i - 768);
    else pack_b_seg(bq2, bk2, bv2, sc16, 128, bias2, i - 1152);
  }
}

// ---------------- scans (2 passes; pass3 folded into scatter) ----------------
__device__ __forceinline__ int block_scan_excl256(int v, int* buf, int t, int* total) {
  buf[t] = v;
  __syncthreads();
#pragma unroll
  for (int off = 1; off < 256; off <<= 1) {
    int add = (t >= off) ? buf[t - off] : 0;
    __syncthreads();
    buf[t] += add;
    __syncthreads();
  }
  int incl = buf[t];
  *total = buf[255];
  __syncthreads();
  return incl - v;
}

__global__ void scan_p1(const int* __restrict__ hist, int* __restrict__ excl,
                        int* __restrict__ bsum, int n) {
  __shared__ int buf[256];
  int t = threadIdx.x;
  int i = blockIdx.x * 256 + t;
  int v = (i < n) ? hist[i] : 0;
  int total;
  int ex = block_scan_excl256(v, buf, t, &total);
  excl[i] = ex;
  if (t == 0) bsum[blockIdx.x] = total;
}

__global__ void scan_p2(int* __restrict__ bsum, int nblk) {
  __shared__ int buf[256];
  int t = threadIdx.x;
  int v = (t < nblk) ? bsum[t] : 0;
  int total;
  int ex = block_scan_excl256(v, buf, t, &total);
  bsum[t] = ex;
}

// scatter (single layer): pos = excl[d] + bsum[d>>8] + rank
__global__ void scatter1l(const int* __restrict__ e, int E, const int* __restrict__ excl,
                          const int* __restrict__ bsum, const int* __restrict__ rank,
                          long long* __restrict__ pairs) {
  int i = blockIdx.x * 256 + threadIdx.x;
  if (i >= E) return;
  int sN = e[i], d = e[E + i];
  int pos = excl[d] + bsum[d >> 8] + rank[i];
  long long val = ((long long)(unsigned)d << 32) | (unsigned)sN;  // x=sN, y=d
  __builtin_nontemporal_store(val, &pairs[pos]);
}

// ---------------- node-level GEMM (fp16 MFMA) + optional hosted histogram ---
// HH: each thread fires one e-edge atomicAdd BEFORE the gemm body and writes
// rank AFTER the C-write -> TCC RMW service overlaps MFMA/LDS compute.
template <int IN, int O, int G, bool HH>
__global__ __launch_bounds__(256, 4) void node_gemm(
    const unsigned short* __restrict__ xb, int N, int NT,
    const unsigned short* __restrict__ wpack, const float* __restrict__ bias6,
    unsigned short* __restrict__ Y1, unsigned short* __restrict__ Y2,
    const int* __restrict__ eH, int EH, int* __restrict__ histH, int* __restrict__ rankH) {
  constexpr int KC = IN / 32;
  constexpr int NCH = O / 16;
  constexpr int CHR = IN / 8;
  constexpr int CM = CHR - 1;
  __shared__ unsigned short tiles[64 * IN];

  int aval = 0;
  int ei = blockIdx.x * 256 + threadIdx.x;
  const bool doA = HH && (ei < EH);
  if (doA) aval = atomicAdd(&histH[eH[EH + ei]], 1);  // fire early

  const int chunk = gridDim.x >> 3;  // grid is a multiple of 8
  const int lb = (blockIdx.x & 7) * chunk + (blockIdx.x >> 3);
  const int t = threadIdx.x, w = t >> 6, ln = t & 63;
  if (lb < NT * G) {
    const int tile = lb / G;
    const int grp = lb % G;
    const int n0 = tile * 64;

    {
      constexpr int RPI = 64 / CHR;
      constexpr int NI = 16 / RPI;
      const int r_in = ln / CHR, c = ln % CHR;
#pragma unroll
      for (int i = 0; i < NI; ++i) {
        int row = w * 16 + i * RPI + r_in;
        int node = min(n0 + row, N - 1);
        int sc = c ^ (row & CM);
        const unsigned short* g = xb + (size_t)node * IN + sc * 8;
        unsigned short* l = &tiles[(size_t)(w * 16 + i * RPI) * IN];
        __builtin_amdgcn_global_load_lds(
            (const __attribute__((address_space(1))) unsigned int*)g,
            (__attribute__((address_space(3))) unsigned int*)l, 16, 0, 0);
      }
    }
    __syncthreads();

    const int col = ln & 15, quad = ln >> 4;
    const int g0 = grp * 8 + w * 2;

    f32x4 acc[2][4];
#pragma unroll
    for (int cc = 0; cc < 2; ++cc)
#pragma unroll
      for (int m = 0; m < 4; ++m) acc[cc][m] = (f32x4){0.f, 0.f, 0.f, 0.f};

#pragma unroll
    for (int kc = 0; kc < KC; ++kc) {
      f16x8 a[4];
#pragma unroll
      for (int m = 0; m < 4; ++m) {
        int row = m * 16 + col;
        int sc = (kc * 4 + quad) ^ (row & CM);
        a[m] = *reinterpret_cast<const f16x8*>(&tiles[(size_t)row * IN + sc * 8]);
      }
#pragma unroll
      for (int cc = 0; cc < 2; ++cc) {
        const f16x8 b = *reinterpret_cast<const f16x8*>(
            wpack + ((size_t)((g0 + cc) * KC + kc) * 64 + ln) * 8);
#pragma unroll
        for (int m = 0; m < 4; ++m)
          acc[cc][m] = __builtin_amdgcn_mfma_f32_16x16x32_f16(a[m], b, acc[cc][m], 0, 0, 0);
      }
    }

#pragma unroll
    for (int cc = 0; cc < 2; ++cc) {
      int gch = g0 + cc;
      int mat = gch / NCH, ncg = gch % NCH;
      unsigned short* Yp = (mat < 3) ? Y1 : Y2;
      int mo = (mat < 3) ? mat : mat - 3;
      float bv = bias6[gch * 16 + col];
      size_t coloff = (size_t)mo * O + ncg * 16 + col;
#pragma unroll
      for (int m = 0; m < 4; ++m)
#pragma unroll
        for (int r = 0; r < 4; ++r) {
          int node = n0 + m * 16 + quad * 4 + r;
          if (node < N) Yp[(size_t)node * (3 * O) + coloff] = f2h(acc[cc][m][r] + bv);
        }
    }
  }

  if (doA) rankH[ei] = aval;  // consume late
}

// ---------------- gather-based edge kernel (packed fp16 math) ----------------
template <int O, int HS>
__global__ __launch_bounds__(512, 6) void edge_attn_kernel(
    const unsigned short* __restrict__ Y1, const unsigned short* __restrict__ Y2,
    const int2* __restrict__ pairs, const int E, float* __restrict__ s) {
  constexpr int NL = HS / 8;
  constexpr int PM = O / 4 - 1;
  __shared__ float ctx[64 * O];
  __shared__ int dstL[64];

  const int chunkB = gridDim.x >> 3;
  const int lb = (blockIdx.x & 7) * chunkB + (blockIdx.x >> 3);
  if (lb * 64 >= E) return;

  const int t = threadIdx.x;
  const int e = t >> 3, head = t & 7;
  const int eG = lb * 64 + e;
  const int eC = min(eG, E - 1);
  const bool valid = eG < E;
  const int2 p = pairs[eC];
  const int sN = p.x, dN = p.y;
  if ((t & 7) == 0) dstL[e] = dN;
  const float dd = fabsf((float)(dN - sN));
  const float ew = (dd > 8.f) ? 1.f : ((dd == 8.f) ? 0.f : -1.f);

  const unsigned short* b1 = Y1 + (size_t)dN * (3 * O) + head * HS;
  const unsigned short* b2 = Y2 + (size_t)sN * (3 * O) + head * HS;

  u32x4 q1[NL], q2[NL], k1[NL], k2[NL], v1[NL], v2[NL];
#pragma unroll
  for (int l = 0; l < NL; ++l) {
    q1[l] = *reinterpret_cast<const u32x4*>(b1 + l * 8);
    q2[l] = *reinterpret_cast<const u32x4*>(b2 + l * 8);
    k1[l] = *reinterpret_cast<const u32x4*>(b1 + O + l * 8);
    k2[l] = *reinterpret_cast<const u32x4*>(b2 + O + l * 8);
    v1[l] = *reinterpret_cast<const u32x4*>(b1 + 2 * O + l * 8);
    v2[l] = *reinterpret_cast<const u32x4*>(b2 + 2 * O + l * 8);
  }

  f32x2 ex2[NL * 4];
  f32x2 sum2 = (f32x2){0.f, 0.f};
#pragma unroll
  for (int l = 0; l < NL; ++l)
#pragma unroll
    for (int d = 0; d < 4; ++d) {
      __half2 qh = __hadd2(ash2(q1[l][d]), ash2(q2[l][d]));
      __half2 kh = __hadd2(ash2(k1[l][d]), ash2(k2[l][d]));
      __half2 qk = __hmul2(qh, kh);  // log2e*scale already folded into k
      f32x2 eo;
      eo.x = exp2f(__low2float(qk));
      eo.y = exp2f(__high2float(qk));
      ex2[l * 4 + d] = eo;
      sum2 += eo;
    }
  const float sum = sum2.x + sum2.y;
  const float rs = valid ? (ew / sum) : 0.f;
  const f32x2 rs2 = (f32x2){rs, rs};
#pragma unroll
  for (int l = 0; l < NL; ++l) {
#pragma unroll
    for (int g2 = 0; g2 < 2; ++g2) {
      __half2 va = __hadd2(ash2(v1[l][g2 * 2]), ash2(v2[l][g2 * 2]));
      __half2 vb = __hadd2(ash2(v1[l][g2 * 2 + 1]), ash2(v2[l][g2 * 2 + 1]));
      f32x2 vva = (f32x2){__low2float(va), __high2float(va)};
      f32x2 vvb = (f32x2){__low2float(vb), __high2float(vb)};
      f32x2 oa = ex2[l * 4 + g2 * 2] * rs2 * vva;
      f32x2 ob = ex2[l * 4 + g2 * 2 + 1] * rs2 * vvb;
      f32x4 o = (f32x4){oa.x, oa.y, ob.x, ob.y};
      int g = l * 2 + g2;
      int pch = (g * 8 + head + e) & PM;
      *reinterpret_cast<f32x4*>(&ctx[e * O + pch * 4]) = o;
    }
  }
  __syncthreads();

  {
    constexpr int GRP = 512 / O;
    constexpr int EPT = 64 / GRP;
    const int hs2 = t & 7;
    const int cs = (t >> 3) & (HS - 1);
    const int colA = hs2 * HS + cs;
    const int seg0 = (t / O) * EPT;
    const int inv = (cs >> 2) * 8 + hs2;
    const int js = cs & 3;
    float run = 0.f;
    int runstart = 0;
    int dcur = dstL[seg0];
#pragma unroll
    for (int i = 0; i < EPT; ++i) {
      int ee = seg0 + i;
      int pch = (inv + ee) & PM;
      run += ctx[ee * O + pch * 4 + js];
      int dnext = (i < EPT - 1) ? dstL[ee + 1] : -1;
      if (dnext != dcur) {
        float* addr = &s[(size_t)dcur * O + colA];
        if (runstart > 0 && i < EPT - 1) *addr = run;
        else atomicAdd(addr, run);
        run = 0.f;
        runstart = i + 1;
        dcur = dnext;
      }
    }
  }
}

// ---------------- finalize (counts read from hist) ----------------
__global__ void finalize_relu_f32h(float* __restrict__ s, const int* __restrict__ cnt,
                                   unsigned short* __restrict__ xbo, int total4, int Odiv4) {
  int i = blockIdx.x * blockDim.x + threadIdx.x;
  if (i >= total4) return;
  int node = i / Odiv4;
  float c = fmaxf((float)cnt[node], 1.0f);
  float4 v = reinterpret_cast<float4*>(s)[i];
  v.x = fmaxf(v.x / c, 0.f);
  v.y = fmaxf(v.y / c, 0.f);
  v.z = fmaxf(v.z / c, 0.f);
  v.w = fmaxf(v.w / c, 0.f);
  reinterpret_cast<float4*>(s)[i] = v;
  ushort4 o = make_ushort4(f2h(v.x), f2h(v.y), f2h(v.z), f2h(v.w));
  reinterpret_cast<ushort4*>(xbo)[i] = o;
}

__global__ void finalize_relu_h(const float* __restrict__ s, const int* __restrict__ cnt,
                                unsigned short* __restrict__ xbo, int total4, int Odiv4) {
  int i = blockIdx.x * blockDim.x + threadIdx.x;
  if (i >= total4) return;
  int node = i / Odiv4;
  float c = fmaxf((float)cnt[node], 1.0f);
  float4 v = reinterpret_cast<const float4*>(s)[i];
  ushort4 o = make_ushort4(f2h(fmaxf(v.x / c, 0.f)), f2h(fmaxf(v.y / c, 0.f)),
                           f2h(fmaxf(v.z / c, 0.f)), f2h(fmaxf(v.w / c, 0.f)));
  reinterpret_cast<ushort4*>(xbo)[i] = o;
}

__global__ void finalize_add_relu(float* __restrict__ out, const float* __restrict__ x0,
                                  const int* __restrict__ cnt, int total4, int Odiv4) {
  int i = blockIdx.x * blockDim.x + threadIdx.x;
  if (i >= total4) return;
  int node = i / Odiv4;
  float c = fmaxf((float)cnt[node], 1.0f);
  float4 v = reinterpret_cast<float4*>(out)[i];
  float4 r = reinterpret_cast<const float4*>(x0)[i];
  v.x = fmaxf(v.x / c + r.x, 0.f);
  v.y = fmaxf(v.y / c + r.y, 0.f);
  v.z = fmaxf(v.z / c + r.z, 0.f);
  v.w = fmaxf(v.w / c + r.w, 0.f);
  reinterpret_cast<float4*>(out)[i] = v;
}

extern "C" void kernel_launch(void* const* d_in, const int* in_sizes, int n_in,
                              void* d_out, int out_size, void* d_ws, size_t ws_size,
                              hipStream_t stream) {
  const float* x = (const float*)d_in[0];
  const int* e0 = (const int*)d_in[1];
  const int* e1 = (const int*)d_in[2];
  const int* e2 = (const int*)d_in[3];
  const float* wq0 = (const float*)d_in[5];
  const float* bq0 = (const float*)d_in[6];
  const float* wk0 = (const float*)d_in[7];
  const float* bk0 = (const float*)d_in[8];
  const float* wv0 = (const float*)d_in[9];
  const float* bv0 = (const float*)d_in[10];
  const float* wq1 = (const float*)d_in[11];
  const float* bq1 = (const float*)d_in[12];
  const float* wk1 = (const float*)d_in[13];
  const float* bk1 = (const float*)d_in[14];
  const float* wv1 = (const float*)d_in[15];
  const float* bv1 = (const float*)d_in[16];
  const float* wq2 = (const float*)d_in[17];
  const float* bq2 = (const float*)d_in[18];
  const float* wk2 = (const float*)d_in[19];
  const float* bk2 = (const float*)d_in[20];
  const float* wv2 = (const float*)d_in[21];
  const float* bv2 = (const float*)d_in[22];

  const int N = in_sizes[0] / 128;  // 50000
  const int E = in_sizes[1] / 2;    // 500000
  const int NBLK = (N + 255) / 256;
  const int NP = NBLK * 256;
  const float LOG2E = 1.4426950408889634f;
  const float SC16 = 0.25f * LOG2E;                 // 1/sqrt(16) * log2e
  const float SC8 = 0.35355339059327373f * LOG2E;   // 1/sqrt(8)  * log2e

  // ---- workspace carve-up ----
  unsigned short* wp0 = (unsigned short*)d_ws;       // 98304 shorts
  unsigned short* wp1 = wp0 + 98304;                 // 49152
  unsigned short* wp2 = wp1 + 49152;                 // 49152
  float* bias0 = (float*)(wp2 + 49152);              // 768
  float* bias1 = bias0 + 768;                        // 384
  float* bias2 = bias1 + 384;                        // 768
  unsigned short* xb = (unsigned short*)(bias2 + 768);  // N*128
  unsigned short* Y1 = xb + (size_t)N * 128;         // N*384
  unsigned short* Y2 = Y1 + (size_t)N * 384;         // N*384
  float* s0 = (float*)(Y2 + (size_t)N * 384);        // N*128
  float* s1 = s0 + (size_t)N * 128;                  // N*64
  int* hist = (int*)(s1 + (size_t)N * 64);           // 3*NP
  int* excl = hist + 3 * (size_t)NP;                 // 3*NP
  int* bsum = excl + 3 * (size_t)NP;                 // 768
  int* rank = bsum + 768;                            // 3*E
  long long* pairs = (long long*)(rank + 3 * (size_t)E + 2);  // 3*E (8B aligned)

  hipMemsetAsync(hist, 0, 3 * (size_t)NP * sizeof(int), stream);

  // preproc: streaming + e0 hist atomics
  preproc<<<2048, 256, 0, stream>>>(
      e0, E, hist, rank,
      (uint4*)s0, N * 48, (uint4*)d_out, out_size / 4,
      x, xb, N * 16,
      wq0, wk0, wv0, wq1, wk1, wv1, wq2, wk2, wv2, wp0, wp1, wp2,
      bq0, bk0, bv0, bq1, bk1, bv1, bq2, bk2, bv2, bias0, bias1, bias2,
      SC16, SC8);

  const int NT = (N + 63) / 64;
  const int EBK = (E + 63) / 64;
  const int EGRID = 8 * ((EBK + 7) / 8);
  const int GG6 = 8 * ((NT * 6 + 7) / 8);
  const int GG3 = 8 * ((NT * 3 + 7) / 8);
  const int EB256 = (E + 255) / 256;

  // layer-0 sort (scan + scatter), then gemm0 hosting e1 hist
  scan_p1<<<NBLK, 256, 0, stream>>>(hist, excl, bsum, N);
  scan_p2<<<1, 256, 0, stream>>>(bsum, NBLK);
  scatter1l<<<EB256, 256, 0, stream>>>(e0, E, excl, bsum, rank, pairs);

  node_gemm<128, 128, 6, true><<<GG6, 256, 0, stream>>>(
      xb, N, NT, wp0, bias0, Y1, Y2, e1, E, hist + NP, rank + E);

  // layer-1 sort just-in-time (hist[1] complete after gemm0)
  scan_p1<<<NBLK, 256, 0, stream>>>(hist + NP, excl + NP, bsum + 256, N);
  scan_p2<<<1, 256, 0, stream>>>(bsum + 256, NBLK);
  scatter1l<<<EB256, 256, 0, stream>>>(e1, E, excl + NP, bsum + 256, rank + E, pairs + E);

  edge_attn_kernel<128, 16><<<EGRID, 512, 0, stream>>>(Y1, Y2, (const int2*)pairs, E, s0);
  finalize_relu_f32h<<<(N * 32 + 255) / 256, 256, 0, stream>>>(s0, hist, xb, N * 32, 32);

  node_gemm<128, 64, 3, true><<<GG3, 256, 0, stream>>>(
      xb, N, NT, wp1, bias1, Y1, Y2, e2, E, hist + 2 * NP, rank + 2 * (size_t)E);

  // layer-2 sort just-in-time
  scan_p1<<<NBLK, 256, 0, stream>>>(hist + 2 * NP, excl + 2 * NP, bsum + 512, N);
  scan_p2<<<1, 256, 0, stream>>>(bsum + 512, NBLK);
  scatter1l<<<EB256, 256, 0, stream>>>(e2, E, excl + 2 * NP, bsum + 512, rank + 2 * (size_t)E,
                                       pairs + 2 * (size_t)E);

  edge_attn_kernel<64, 8><<<EGRID, 512, 0, stream>>>(Y1, Y2, (const int2*)(pairs + E), E, s1);
  finalize_relu_h<<<(N * 16 + 255) / 256, 256, 0, stream>>>(s1, hist + NP, xb, N * 16, 16);

  node_gemm<64, 128, 6, false><<<GG6, 256, 0, stream>>>(
      xb, N, NT, wp2, bias2, Y1, Y2, nullptr, 0, nullptr, nullptr);
  edge_attn_kernel<128, 16><<<EGRID, 512, 0, stream>>>(Y1, Y2, (const int2*)(pairs + 2 * (size_t)E),
                                                       E, (float*)d_out);
  finalize_add_relu<<<(N * 32 + 255) / 256, 256, 0, stream>>>((float*)d_out, s0, hist + 2 * NP,
                                                              N * 32, 32);
}

// Round 11
// 513.967 us; speedup vs baseline: 1.0264x; 1.0264x over previous
//
#include <hip/hip_runtime.h>
#include <hip/hip_fp16.h>

// EdgeConvEncoder R18b (identical to R18; previous bench was an infra
// failure — "container failed twice", no counters. Audit found no fault
// source; resubmitting.)
//  - preproc keeps ALL hist atomics (R17 proved splitting them across kernels
//    loses) but sheds the 64MB of streaming zeros: R16 counters showed the
//    hist RMW thrash drags preproc's streaming to 2.1 TB/s, so the zeros pay
//    atomic-pace tax. They move to scatter3 (write-only, latency-bound,
//    idle store BW; no RMW stream -> no R15-style interference).
//  - scan_pass3/rowptr eliminated: scatter computes pos = excl[d] +
//    bsum[d>>8] + rank (R17's verified arithmetic); finalize reads counts
//    directly from hist.
//  - edge_attn unchanged (gather-service ceiling ~69.5us, 4 variants tied).

typedef _Float16 f16x8 __attribute__((ext_vector_type(8)));
typedef unsigned int u32x4 __attribute__((ext_vector_type(4)));
typedef float f32x4 __attribute__((ext_vector_type(4)));
typedef float f32x2 __attribute__((ext_vector_type(2)));

__device__ __forceinline__ unsigned short f2h(float f) {
  __half h = __float2half(f);
  return *reinterpret_cast<unsigned short*>(&h);
}
__device__ __forceinline__ __half2 ash2(unsigned w) {
  return *reinterpret_cast<__half2*>(&w);
}

// ---------------- weight packing ----------------
__device__ __forceinline__ void pack_w_seg(const float* __restrict__ wq,
                                           const float* __restrict__ wk,
                                           const float* __restrict__ wv,
                                           unsigned short* __restrict__ dst,
                                           int IN, int O, float kscale, int id) {
  int kchunks = IN >> 5, nchunks = O >> 4;
  int total = 6 * nchunks * kchunks * 64;
  if (id >= total) return;
  int lane = id & 63;
  int frag = id >> 6;
  int kc = frag % kchunks;
  int nc = (frag / kchunks) % nchunks;
  int mat = frag / (kchunks * nchunks);
  const float* w = (mat % 3 == 0) ? wq : (mat % 3 == 1) ? wk : wv;
  float mul = (mat % 3 == 1) ? kscale : 1.0f;
  int n = nc * 16 + (lane & 15);
  int k0 = kc * 32 + (lane >> 4) * 8;
  unsigned short tmp[8];
#pragma unroll
  for (int j = 0; j < 8; ++j) {
    int row = k0 + j;
    float bot = w[(size_t)(IN + row) * O + n];
    float val = (mat < 3) ? (w[(size_t)row * O + n] - bot) : bot;
    tmp[j] = f2h(val * mul);
  }
  uint4 o;
  o.x = (unsigned)tmp[0] | ((unsigned)tmp[1] << 16);
  o.y = (unsigned)tmp[2] | ((unsigned)tmp[3] << 16);
  o.z = (unsigned)tmp[4] | ((unsigned)tmp[5] << 16);
  o.w = (unsigned)tmp[6] | ((unsigned)tmp[7] << 16);
  reinterpret_cast<uint4*>(dst)[id] = o;
}

__device__ __forceinline__ void pack_b_seg(const float* __restrict__ bq,
                                           const float* __restrict__ bk,
                                           const float* __restrict__ bv, float kscale, int O,
                                           float* __restrict__ out, int i) {
  int mat = i / O, c = i % O;
  float v = 0.f;
  if (mat == 0) v = bq[c];
  else if (mat == 1) v = bk[c] * kscale;
  else if (mat == 2) v = bv[c];
  out[i] = v;
}

// ---------------- fused preprocessing + 3-layer histogram ----------------
// hist atomics (rank capture) + weight/bias pack + x f32->fp16.
// hist must be zeroed BEFORE this kernel (hipMemsetAsync).
__global__ void preproc(
    const int* __restrict__ e0, const int* __restrict__ e1, const int* __restrict__ e2,
    int E, int* __restrict__ hist, int* __restrict__ rank, int NP,
    const float* __restrict__ x, unsigned short* __restrict__ xb, int n8,
    const float* __restrict__ wq0, const float* __restrict__ wk0, const float* __restrict__ wv0,
    const float* __restrict__ wq1, const float* __restrict__ wk1, const float* __restrict__ wv1,
    const float* __restrict__ wq2, const float* __restrict__ wk2, const float* __restrict__ wv2,
    unsigned short* __restrict__ wp0, unsigned short* __restrict__ wp1,
    unsigned short* __restrict__ wp2,
    const float* __restrict__ bq0, const float* __restrict__ bk0, const float* __restrict__ bv0,
    const float* __restrict__ bq1, const float* __restrict__ bk1, const float* __restrict__ bv1,
    const float* __restrict__ bq2, const float* __restrict__ bk2, const float* __restrict__ bv2,
    float* __restrict__ bias0, float* __restrict__ bias1, float* __restrict__ bias2,
    float sc16, float sc8) {
  const int tid = blockIdx.x * blockDim.x + threadIdx.x;
  const int stride = gridDim.x * blockDim.x;

  // 3-layer edge histogram + rank (atomic returns)
  for (int i = tid; i < E; i += stride) {
    rank[i] = atomicAdd(&hist[e0[E + i]], 1);
    rank[(size_t)E + i] = atomicAdd(&hist[NP + e1[E + i]], 1);
    rank[2 * (size_t)E + i] = atomicAdd(&hist[2 * NP + e2[E + i]], 1);
  }

  for (int j = tid; j < n8; j += stride) {
    float4 a = reinterpret_cast<const float4*>(x)[2 * j];
    float4 b = reinterpret_cast<const float4*>(x)[2 * j + 1];
    uint4 o;
    o.x = (unsigned)f2h(a.x) | ((unsigned)f2h(a.y) << 16);
    o.y = (unsigned)f2h(a.z) | ((unsigned)f2h(a.w) << 16);
    o.z = (unsigned)f2h(b.x) | ((unsigned)f2h(b.y) << 16);
    o.w = (unsigned)f2h(b.z) | ((unsigned)f2h(b.w) << 16);
    reinterpret_cast<uint4*>(xb)[j] = o;
  }
  if (tid < 12288) pack_w_seg(wq0, wk0, wv0, wp0, 128, 128, sc16, tid);
  else if (tid < 18432) pack_w_seg(wq1, wk1, wv1, wp1, 128, 64, sc8, tid - 12288);
  else if (tid < 24576) pack_w_seg(wq2, wk2, wv2, wp2, 64, 128, sc16, tid - 18432);
  else if (tid < 24576 + 1920) {
    int i = tid - 24576;
    if (i < 768) pack_b_seg(bq0, bk0, bv0, sc16, 128, bias0, i);
    else if (i < 1152) pack_b_seg(bq1, bk1, bv1, sc8, 64, bias1, i - 768);
    else pack_b_seg(bq2, bk2, bv2, sc16, 128, bias2, i - 1152);
  }
}

// ---------------- scans (pass3 folded into scatter) ----------------
__device__ __forceinline__ int block_scan_excl256(int v, int* buf, int t, int* total) {
  buf[t] = v;
  __syncthreads();
#pragma unroll
  for (int off = 1; off < 256; off <<= 1) {
    int add = (t >= off) ? buf[t - off] : 0;
    __syncthreads();
    buf[t] += add;
    __syncthreads();
  }
  int incl = buf[t];
  *total = buf[255];
  __syncthreads();
  return incl - v;
}

__global__ void scan_pass1(const int* __restrict__ hist, int* __restrict__ excl,
                           int* __restrict__ bsum, int n, int NP) {
  __shared__ int buf[256];
  int y = blockIdx.y, t = threadIdx.x;
  int i = blockIdx.x * 256 + t;
  int v = (i < n) ? hist[y * NP + i] : 0;
  int total;
  int ex = block_scan_excl256(v, buf, t, &total);
  if (i < NP) excl[y * NP + i] = ex;
  if (t == 0) bsum[y * 256 + blockIdx.x] = total;
}

__global__ void scan_pass2(int* __restrict__ bsum, int nblk) {
  __shared__ int buf[256];
  int y = blockIdx.y, t = threadIdx.x;
  int v = (t < nblk) ? bsum[y * 256 + t] : 0;
  int total;
  int ex = block_scan_excl256(v, buf, t, &total);
  bsum[y * 256 + t] = ex;
}

// scatter + zero-fill: pos = excl[d] + bsum[d>>8] + rank (scan3 folded);
// also zeros s0+s1 and d_out with streaming writes (moved out of preproc —
// they were paying atomic-RMW pace there; here they ride idle store BW).
__global__ void scatter3(const int* __restrict__ e0, const int* __restrict__ e1,
                         const int* __restrict__ e2, int E, const int* __restrict__ excl,
                         const int* __restrict__ bsum, const int* __restrict__ rank,
                         long long* __restrict__ pairs, int NP,
                         uint4* __restrict__ za, int na, uint4* __restrict__ zb, int nb) {
  int y = blockIdx.y;
  const int* e = (y == 0) ? e0 : (y == 1) ? e1 : e2;
  int i = blockIdx.x * 256 + threadIdx.x;
  if (i < E) {
    int sN = e[i], d = e[E + i];
    int pos = excl[y * NP + d] + bsum[y * 256 + (d >> 8)] + rank[(size_t)y * E + i];
    long long val = ((long long)(unsigned)d << 32) | (unsigned)sN;  // x=sN, y=d
    __builtin_nontemporal_store(val, &pairs[(size_t)y * E + pos]);
  }
  // streaming zero-fill across the whole dim3 grid
  const int gid = (blockIdx.y * gridDim.x + blockIdx.x) * 256 + threadIdx.x;
  const int gstride = gridDim.x * gridDim.y * 256;
  const uint4 Z = make_uint4(0u, 0u, 0u, 0u);
  for (int j = gid; j < na; j += gstride) za[j] = Z;
  for (int j = gid; j < nb; j += gstride) zb[j] = Z;
}

// ---------------- node-level GEMM (fp16 MFMA) ----------------
template <int IN, int O, int G>
__global__ __launch_bounds__(256, 4) void node_gemm(
    const unsigned short* __restrict__ xb, int N, int NT,
    const unsigned short* __restrict__ wpack, const float* __restrict__ bias6,
    unsigned short* __restrict__ Y1, unsigned short* __restrict__ Y2) {
  constexpr int KC = IN / 32;
  constexpr int NCH = O / 16;
  constexpr int CHR = IN / 8;
  constexpr int CM = CHR - 1;
  __shared__ unsigned short tiles[64 * IN];

  const int chunk = gridDim.x >> 3;  // grid is a multiple of 8
  const int lb = (blockIdx.x & 7) * chunk + (blockIdx.x >> 3);
  if (lb >= NT * G) return;
  const int tile = lb / G;
  const int grp = lb % G;

  const int t = threadIdx.x, w = t >> 6, ln = t & 63;
  const int n0 = tile * 64;

  {
    constexpr int RPI = 64 / CHR;
    constexpr int NI = 16 / RPI;
    const int r_in = ln / CHR, c = ln % CHR;
#pragma unroll
    for (int i = 0; i < NI; ++i) {
      int row = w * 16 + i * RPI + r_in;
      int node = min(n0 + row, N - 1);
      int sc = c ^ (row & CM);
      const unsigned short* g = xb + (size_t)node * IN + sc * 8;
      unsigned short* l = &tiles[(size_t)(w * 16 + i * RPI) * IN];
      __builtin_amdgcn_global_load_lds(
          (const __attribute__((address_space(1))) unsigned int*)g,
          (__attribute__((address_space(3))) unsigned int*)l, 16, 0, 0);
    }
  }
  __syncthreads();

  const int col = ln & 15, quad = ln >> 4;
  const int g0 = grp * 8 + w * 2;

  f32x4 acc[2][4];
#pragma unroll
  for (int cc = 0; cc < 2; ++cc)
#pragma unroll
    for (int m = 0; m < 4; ++m) acc[cc][m] = (f32x4){0.f, 0.f, 0.f, 0.f};

#pragma unroll
  for (int kc = 0; kc < KC; ++kc) {
    f16x8 a[4];
#pragma unroll
    for (int m = 0; m < 4; ++m) {
      int row = m * 16 + col;
      int sc = (kc * 4 + quad) ^ (row & CM);
      a[m] = *reinterpret_cast<const f16x8*>(&tiles[(size_t)row * IN + sc * 8]);
    }
#pragma unroll
    for (int cc = 0; cc < 2; ++cc) {
      const f16x8 b = *reinterpret_cast<const f16x8*>(
          wpack + ((size_t)((g0 + cc) * KC + kc) * 64 + ln) * 8);
#pragma unroll
      for (int m = 0; m < 4; ++m)
        acc[cc][m] = __builtin_amdgcn_mfma_f32_16x16x32_f16(a[m], b, acc[cc][m], 0, 0, 0);
    }
  }

#pragma unroll
  for (int cc = 0; cc < 2; ++cc) {
    int gch = g0 + cc;
    int mat = gch / NCH, ncg = gch % NCH;
    unsigned short* Yp = (mat < 3) ? Y1 : Y2;
    int mo = (mat < 3) ? mat : mat - 3;
    float bv = bias6[gch * 16 + col];
    size_t coloff = (size_t)mo * O + ncg * 16 + col;
#pragma unroll
    for (int m = 0; m < 4; ++m)
#pragma unroll
      for (int r = 0; r < 4; ++r) {
        int node = n0 + m * 16 + quad * 4 + r;
        if (node < N) Yp[(size_t)node * (3 * O) + coloff] = f2h(acc[cc][m][r] + bv);
      }
  }
}

// ---------------- gather-based edge kernel (packed fp16 math) ----------------
template <int O, int HS>
__global__ __launch_bounds__(512, 6) void edge_attn_kernel(
    const unsigned short* __restrict__ Y1, const unsigned short* __restrict__ Y2,
    const int2* __restrict__ pairs, const int E, float* __restrict__ s) {
  constexpr int NL = HS / 8;
  constexpr int PM = O / 4 - 1;
  __shared__ float ctx[64 * O];
  __shared__ int dstL[64];

  const int chunkB = gridDim.x >> 3;
  const int lb = (blockIdx.x & 7) * chunkB + (blockIdx.x >> 3);
  if (lb * 64 >= E) return;

  const int t = threadIdx.x;
  const int e = t >> 3, head = t & 7;
  const int eG = lb * 64 + e;
  const int eC = min(eG, E - 1);
  const bool valid = eG < E;
  const int2 p = pairs[eC];
  const int sN = p.x, dN = p.y;
  if ((t & 7) == 0) dstL[e] = dN;
  const float dd = fabsf((float)(dN - sN));
  const float ew = (dd > 8.f) ? 1.f : ((dd == 8.f) ? 0.f : -1.f);

  const unsigned short* b1 = Y1 + (size_t)dN * (3 * O) + head * HS;
  const unsigned short* b2 = Y2 + (size_t)sN * (3 * O) + head * HS;

  u32x4 q1[NL], q2[NL], k1[NL], k2[NL], v1[NL], v2[NL];
#pragma unroll
  for (int l = 0; l < NL; ++l) {
    q1[l] = *reinterpret_cast<const u32x4*>(b1 + l * 8);
    q2[l] = *reinterpret_cast<const u32x4*>(b2 + l * 8);
    k1[l] = *reinterpret_cast<const u32x4*>(b1 + O + l * 8);
    k2[l] = *reinterpret_cast<const u32x4*>(b2 + O + l * 8);
    v1[l] = *reinterpret_cast<const u32x4*>(b1 + 2 * O + l * 8);
    v2[l] = *reinterpret_cast<const u32x4*>(b2 + 2 * O + l * 8);
  }

  f32x2 ex2[NL * 4];
  f32x2 sum2 = (f32x2){0.f, 0.f};
#pragma unroll
  for (int l = 0; l < NL; ++l)
#pragma unroll
    for (int d = 0; d < 4; ++d) {
      __half2 qh = __hadd2(ash2(q1[l][d]), ash2(q2[l][d]));
      __half2 kh = __hadd2(ash2(k1[l][d]), ash2(k2[l][d]));
      __half2 qk = __hmul2(qh, kh);  // log2e*scale already folded into k
      f32x2 eo;
      eo.x = exp2f(__low2float(qk));
      eo.y = exp2f(__high2float(qk));
      ex2[l * 4 + d] = eo;
      sum2 += eo;
    }
  const float sum = sum2.x + sum2.y;
  const float rs = valid ? (ew / sum) : 0.f;
  const f32x2 rs2 = (f32x2){rs, rs};
#pragma unroll
  for (int l = 0; l < NL; ++l) {
#pragma unroll
    for (int g2 = 0; g2 < 2; ++g2) {
      __half2 va = __hadd2(ash2(v1[l][g2 * 2]), ash2(v2[l][g2 * 2]));
      __half2 vb = __hadd2(ash2(v1[l][g2 * 2 + 1]), ash2(v2[l][g2 * 2 + 1]));
      f32x2 vva = (f32x2){__low2float(va), __high2float(va)};
      f32x2 vvb = (f32x2){__low2float(vb), __high2float(vb)};
      f32x2 oa = ex2[l * 4 + g2 * 2] * rs2 * vva;
      f32x2 ob = ex2[l * 4 + g2 * 2 + 1] * rs2 * vvb;
      f32x4 o = (f32x4){oa.x, oa.y, ob.x, ob.y};
      int g = l * 2 + g2;
      int pch = (g * 8 + head + e) & PM;
      *reinterpret_cast<f32x4*>(&ctx[e * O + pch * 4]) = o;
    }
  }
  __syncthreads();

  {
    constexpr int GRP = 512 / O;
    constexpr int EPT = 64 / GRP;
    const int hs2 = t & 7;
    const int cs = (t >> 3) & (HS - 1);
    const int colA = hs2 * HS + cs;
    const int seg0 = (t / O) * EPT;
    const int inv = (cs >> 2) * 8 + hs2;
    const int js = cs & 3;
    float run = 0.f;
    int runstart = 0;
    int dcur = dstL[seg0];
#pragma unroll
    for (int i = 0; i < EPT; ++i) {
      int ee = seg0 + i;
      int pch = (inv + ee) & PM;
      run += ctx[ee * O + pch * 4 + js];
      int dnext = (i < EPT - 1) ? dstL[ee + 1] : -1;
      if (dnext != dcur) {
        float* addr = &s[(size_t)dcur * O + colA];
        if (runstart > 0 && i < EPT - 1) *addr = run;
        else atomicAdd(addr, run);
        run = 0.f;
        runstart = i + 1;
        dcur = dnext;
      }
    }
  }
}

// ---------------- finalize (counts read from hist) ----------------
__global__ void finalize_relu_f32h(float* __restrict__ s, const int* __restrict__ cnt,
                                   unsigned short* __restrict__ xbo, int total4, int Odiv4) {
  int i = blockIdx.x * blockDim.x + threadIdx.x;
  if (i >= total4) return;
  int node = i / Odiv4;
  float c = fmaxf((float)cnt[node], 1.0f);
  float4 v = reinterpret_cast<float4*>(s)[i];
  v.x = fmaxf(v.x / c, 0.f);
  v.y = fmaxf(v.y / c, 0.f);
  v.z = fmaxf(v.z / c, 0.f);
  v.w = fmaxf(v.w / c, 0.f);
  reinterpret_cast<float4*>(s)[i] = v;
  ushort4 o = make_ushort4(f2h(v.x), f2h(v.y), f2h(v.z), f2h(v.w));
  reinterpret_cast<ushort4*>(xbo)[i] = o;
}

__global__ void finalize_relu_h(const float* __restrict__ s, const int* __restrict__ cnt,
                                unsigned short* __restrict__ xbo, int total4, int Odiv4) {
  int i = blockIdx.x * blockDim.x + threadIdx.x;
  if (i >= total4) return;
  int node = i / Odiv4;
  float c = fmaxf((float)cnt[node], 1.0f);
  float4 v = reinterpret_cast<const float4*>(s)[i];
  ushort4 o = make_ushort4(f2h(fmaxf(v.x / c, 0.f)), f2h(fmaxf(v.y / c, 0.f)),
                           f2h(fmaxf(v.z / c, 0.f)), f2h(fmaxf(v.w / c, 0.f)));
  reinterpret_cast<ushort4*>(xbo)[i] = o;
}

__global__ void finalize_add_relu(float* __restrict__ out, const float* __restrict__ x0,
                                  const int* __restrict__ cnt, int total4, int Odiv4) {
  int i = blockIdx.x * blockDim.x + threadIdx.x;
  if (i >= total4) return;
  int node = i / Odiv4;
  float c = fmaxf((float)cnt[node], 1.0f);
  float4 v = reinterpret_cast<float4*>(out)[i];
  float4 r = reinterpret_cast<const float4*>(x0)[i];
  v.x = fmaxf(v.x / c + r.x, 0.f);
  v.y = fmaxf(v.y / c + r.y, 0.f);
  v.z = fmaxf(v.z / c + r.z, 0.f);
  v.w = fmaxf(v.w / c + r.w, 0.f);
  reinterpret_cast<float4*>(out)[i] = v;
}

extern "C" void kernel_launch(void* const* d_in, const int* in_sizes, int n_in,
                              void* d_out, int out_size, void* d_ws, size_t ws_size,
                              hipStream_t stream) {
  const float* x = (const float*)d_in[0];
  const int* e0 = (const int*)d_in[1];
  const int* e1 = (const int*)d_in[2];
  const int* e2 = (const int*)d_in[3];
  const float* wq0 = (const float*)d_in[5];
  const float* bq0 = (const float*)d_in[6];
  const float* wk0 = (const float*)d_in[7];
  const float* bk0 = (const float*)d_in[8];
  const float* wv0 = (const float*)d_in[9];
  const float* bv0 = (const float*)d_in[10];
  const float* wq1 = (const float*)d_in[11];
  const float* bq1 = (const float*)d_in[12];
  const float* wk1 = (const float*)d_in[13];
  const float* bk1 = (const float*)d_in[14];
  const float* wv1 = (const float*)d_in[15];
  const float* bv1 = (const float*)d_in[16];
  const float* wq2 = (const float*)d_in[17];
  const float* bq2 = (const float*)d_in[18];
  const float* wk2 = (const float*)d_in[19];
  const float* bk2 = (const float*)d_in[20];
  const float* wv2 = (const float*)d_in[21];
  const float* bv2 = (const float*)d_in[22];

  const int N = in_sizes[0] / 128;  // 50000
  const int E = in_sizes[1] / 2;    // 500000
  const int NBLK = (N + 255) / 256;
  const int NP = NBLK * 256;
  const float LOG2E = 1.4426950408889634f;
  const float SC16 = 0.25f * LOG2E;                 // 1/sqrt(16) * log2e
  const float SC8 = 0.35355339059327373f * LOG2E;   // 1/sqrt(8)  * log2e

  // ---- workspace carve-up ----
  unsigned short* wp0 = (unsigned short*)d_ws;       // 98304 shorts
  unsigned short* wp1 = wp0 + 98304;                 // 49152
  unsigned short* wp2 = wp1 + 49152;                 // 49152
  float* bias0 = (float*)(wp2 + 49152);              // 768
  float* bias1 = bias0 + 768;                        // 384
  float* bias2 = bias1 + 384;                        // 768
  unsigned short* xb = (unsigned short*)(bias2 + 768);  // N*128
  unsigned short* Y1 = xb + (size_t)N * 128;         // N*384
  unsigned short* Y2 = Y1 + (size_t)N * 384;         // N*384
  float* s0 = (float*)(Y2 + (size_t)N * 384);        // N*128
  float* s1 = s0 + (size_t)N * 128;                  // N*64
  int* hist = (int*)(s1 + (size_t)N * 64);           // 3*NP
  int* excl = hist + 3 * (size_t)NP;                 // 3*NP
  int* bsum = excl + 3 * (size_t)NP;                 // 768
  int* rank = bsum + 768;                            // 3*E
  long long* pairs = (long long*)(rank + 3 * (size_t)E + 2);  // 3*E (8B aligned)

  hipMemsetAsync(hist, 0, 3 * (size_t)NP * sizeof(int), stream);

  // preproc: hist atomics + weight/bias pack + x->fp16 (zeros moved out)
  preproc<<<2048, 256, 0, stream>>>(
      e0, e1, e2, E, hist, rank, NP,
      x, xb, N * 16,
      wq0, wk0, wv0, wq1, wk1, wv1, wq2, wk2, wv2, wp0, wp1, wp2,
      bq0, bk0, bv0, bq1, bk1, bv1, bq2, bk2, bv2, bias0, bias1, bias2,
      SC16, SC8);

  scan_pass1<<<dim3(NBLK, 3), 256, 0, stream>>>(hist, excl, bsum, N, NP);
  scan_pass2<<<dim3(1, 3), 256, 0, stream>>>(bsum, NBLK);

  const int EB256 = (E + 255) / 256;
  // scatter (scan3 folded) + streaming zeros of s0+s1 and d_out
  scatter3<<<dim3(EB256, 3), 256, 0, stream>>>(e0, e1, e2, E, excl, bsum, rank, pairs, NP,
                                               (uint4*)s0, N * 48, (uint4*)d_out, out_size / 4);

  const int NT = (N + 63) / 64;
  const int EBK = (E + 63) / 64;
  const int EGRID = 8 * ((EBK + 7) / 8);
  const int GG6 = 8 * ((NT * 6 + 7) / 8);
  const int GG3 = 8 * ((NT * 3 + 7) / 8);

  // Layer 0: IN=128, O=128, HS=16
  node_gemm<128, 128, 6><<<GG6, 256, 0, stream>>>(xb, N, NT, wp0, bias0, Y1, Y2);
  edge_attn_kernel<128, 16><<<EGRID, 512, 0, stream>>>(Y1, Y2, (const int2*)pairs, E, s0);
  finalize_relu_f32h<<<(N * 32 + 255) / 256, 256, 0, stream>>>(s0, hist, xb, N * 32, 32);
  // Layer 1: IN=128, O=64, HS=8
  node_gemm<128, 64, 3><<<GG3, 256, 0, stream>>>(xb, N, NT, wp1, bias1, Y1, Y2);
  edge_attn_kernel<64, 8><<<EGRID, 512, 0, stream>>>(Y1, Y2, (const int2*)(pairs + E), E, s1);
  finalize_relu_h<<<(N * 16 + 255) / 256, 256, 0, stream>>>(s1, hist + NP, xb, N * 16, 16);
  // Layer 2: IN=64, O=128, HS=16 -> accumulate into d_out
  node_gemm<64, 128, 6><<<GG6, 256, 0, stream>>>(xb, N, NT, wp2, bias2, Y1, Y2);
  edge_attn_kernel<128, 16><<<EGRID, 512, 0, stream>>>(Y1, Y2, (const int2*)(pairs + 2 * (size_t)E),
                                                       E, (float*)d_out);
  finalize_add_relu<<<(N * 32 + 255) / 256, 256, 0, stream>>>((float*)d_out, s0, hist + 2 * NP,
                                                              N * 32, 32);
}